// Round 3
// baseline (393.887 us; speedup 1.0000x reference)
//
#include <hip/hip_runtime.h>
#include <hip/hip_bf16.h>

// Problem constants
#define S_LEN 4096
#define DMODEL 2048
#define NH 16
#define NKV 4
#define HD 128
#define QKV_N 3072   // merged QKV projection width: 2048 Q | 512 K | 512 V

typedef __bf16 bf16x8 __attribute__((ext_vector_type(8)));
typedef float f32x4 __attribute__((ext_vector_type(4)));
typedef unsigned short u16x8 __attribute__((ext_vector_type(8)));
typedef unsigned short u16x4 __attribute__((ext_vector_type(4)));
typedef unsigned int u32x4 __attribute__((ext_vector_type(4)));

__device__ __forceinline__ unsigned short f2bf(float f) {
    unsigned int u = __builtin_bit_cast(unsigned int, f);
    u += 0x7fffu + ((u >> 16) & 1u);   // round-to-nearest-even
    return (unsigned short)(u >> 16);
}
__device__ __forceinline__ float bf2f(unsigned short h) {
    unsigned int u = ((unsigned int)h) << 16;
    return __builtin_bit_cast(float, u);
}

// Single-instruction packed f32x2 -> bf16x2 (RTNE).
__device__ __forceinline__ unsigned int cvt_pk_bf16(float lo, float hi) {
    unsigned int r;
    asm("v_cvt_pk_bf16_f32 %0, %1, %2" : "=v"(r) : "v"(lo), "v"(hi));
    return r;
}

// Raw v_exp_f32 (2^x); skips ocml denorm fixup.
__device__ __forceinline__ float fast_exp2(float x) {
    float r;
    asm("v_exp_f32 %0, %1" : "=v"(r) : "v"(x));
    return r;
}

__device__ __forceinline__ f32x4 mfma16(bf16x8 a, bf16x8 b, f32x4 c) {
    return __builtin_amdgcn_mfma_f32_16x16x32_bf16(a, b, c, 0, 0, 0);
}

// Async global->LDS DMA, 16B per lane. LDS dest = wave-uniform base + lane*16.
__device__ __forceinline__ void async16(unsigned short* lds, const unsigned short* g) {
    __builtin_amdgcn_global_load_lds((__attribute__((address_space(1))) void*)g,
                                     (__attribute__((address_space(3))) void*)lds,
                                     16, 0, 0);
}

// ---------------------------------------------------------------------------
// fp32 -> bf16 elementwise convert (4 elems/thread, float4 loads)
// ---------------------------------------------------------------------------
__global__ __launch_bounds__(256) void conv_f32_bf16(
    const float* __restrict__ in, unsigned short* __restrict__ out, int n4) {
    int i = blockIdx.x * 256 + threadIdx.x;
    if (i >= n4) return;
    float4 v = *(const float4*)&in[(size_t)i * 4];
    u16x4 o;
    o[0] = f2bf(v.x); o[1] = f2bf(v.y); o[2] = f2bf(v.z); o[3] = f2bf(v.w);
    *(u16x4*)&out[(size_t)i * 4] = o;
}

// ---------------------------------------------------------------------------
// Tiled transpose fp32 in[R][C] -> bf16 out[C][R]. R, C multiples of 32.
// ---------------------------------------------------------------------------
__global__ __launch_bounds__(1024) void transpose_f32_bf16(
    const float* __restrict__ in, unsigned short* __restrict__ out,
    int R, int C) {
    __shared__ float tile[32][33];
    int x = blockIdx.x * 32 + threadIdx.x;
    int y = blockIdx.y * 32 + threadIdx.y;
    tile[threadIdx.y][threadIdx.x] = in[(size_t)y * C + x];
    __syncthreads();
    int ox = blockIdx.y * 32 + threadIdx.x;
    int oy = blockIdx.x * 32 + threadIdx.y;
    out[(size_t)oy * R + ox] = f2bf(tile[threadIdx.x][threadIdx.y]);
}

// ---------------------------------------------------------------------------
// Tiled bf16 transpose with input row stride: in[y*ldin + x] (y<R rows, x<C
// cols) -> out[C][R] contiguous.
// ---------------------------------------------------------------------------
__global__ __launch_bounds__(1024) void transpose_bf16(
    const unsigned short* __restrict__ in, unsigned short* __restrict__ out,
    int R, int C, int ldin) {
    __shared__ unsigned short tile[32][33];
    int x = blockIdx.x * 32 + threadIdx.x;
    int y = blockIdx.y * 32 + threadIdx.y;
    tile[threadIdx.y][threadIdx.x] = in[(size_t)y * ldin + x];
    __syncthreads();
    int ox = blockIdx.y * 32 + threadIdx.x;
    int oy = blockIdx.x * 32 + threadIdx.y;
    out[(size_t)oy * R + ox] = tile[threadIdx.x][threadIdx.y];
}

// ---------------------------------------------------------------------------
// C[M,N] = A[M,K] * B[K,N], B given transposed (Bt[N][K]). bf16 in, fp32
// accumulate, OutT out. 128x128 tile, BK=32, 4 waves of 64x64.
// ---------------------------------------------------------------------------
template <typename OutT>
__global__ __launch_bounds__(256) void gemm_bt(
    const unsigned short* __restrict__ A, const unsigned short* __restrict__ Bt,
    OutT* __restrict__ C, int N, int K) {
    __shared__ __align__(16) unsigned short As[2][128 * 32];  // 8 KB per buf
    __shared__ __align__(16) unsigned short Bs[2][128 * 32];
    const int tid = threadIdx.x;
    const int wave = tid >> 6, lane = tid & 63, quad = lane >> 4, l16 = lane & 15;
    const int m0 = blockIdx.x * 128, n0 = blockIdx.y * 128;
    const int waveM = (wave & 1) * 64, waveN = (wave >> 1) * 64;
    f32x4 acc[4][4] = {};

    auto stage = [&](int k0, int b) {
#pragma unroll
        for (int u = 0; u < 2; u++) {
            const int seg = wave * 2 + u;
            const int idx = seg * 64 + lane;
            const int r = idx >> 2, c = idx & 3;  // granule (r, c): 4x16B per row
            async16(&As[b][seg * 512], &A[(size_t)(m0 + r) * K + k0 + c * 8]);
            async16(&Bs[b][seg * 512], &Bt[(size_t)(n0 + r) * K + k0 + c * 8]);
        }
    };

    const int niter = K / 32;
    stage(0, 0);
    __syncthreads();  // drains vmcnt -> buf0 ready
    for (int it = 0; it < niter; it++) {
        const int b = it & 1;
        if (it + 1 < niter) stage((it + 1) * 32, b ^ 1);
        bf16x8 af[4], bfv[4];
#pragma unroll
        for (int i = 0; i < 4; i++)
            af[i] = *(const bf16x8*)&As[b][(waveM + i * 16 + l16) * 32 + quad * 8];
#pragma unroll
        for (int j = 0; j < 4; j++)
            bfv[j] = *(const bf16x8*)&Bs[b][(waveN + j * 16 + l16) * 32 + quad * 8];
#pragma unroll
        for (int i = 0; i < 4; i++)
#pragma unroll
            for (int j = 0; j < 4; j++)
                acc[i][j] = mfma16(af[i], bfv[j], acc[i][j]);
        __syncthreads();  // drains prefetch (issued ~compute-phase ago) + sync
    }
    // C/D layout: col = lane&15, row = quad*4 + reg (verified m89/m91)
#pragma unroll
    for (int i = 0; i < 4; i++)
#pragma unroll
        for (int j = 0; j < 4; j++)
#pragma unroll
            for (int r = 0; r < 4; r++) {
                int row = m0 + waveM + i * 16 + quad * 4 + r;
                int col = n0 + waveN + j * 16 + l16;
                if constexpr (sizeof(OutT) == 2)
                    C[(size_t)row * N + col] = f2bf(acc[i][j][r]);
                else
                    C[(size_t)row * N + col] = acc[i][j][r];
            }
}

// ---------------------------------------------------------------------------
// RoPE in-place on bf16 X[S][...], row stride `stride` elements; head count
// 2^log2nh at cols h*128. cos/sin fp32 [S][128].
// ---------------------------------------------------------------------------
__global__ __launch_bounds__(256) void rope_kernel(
    unsigned short* __restrict__ X, const float* __restrict__ cb,
    const float* __restrict__ sb, int log2nh, int stride) {
    int idx = blockIdx.x * 256 + threadIdx.x;
    int d = idx & 63;
    int h = (idx >> 6) & ((1 << log2nh) - 1);
    int s = idx >> (6 + log2nh);
    size_t base = (size_t)s * stride + h * HD + d;
    float a = bf2f(X[base]);
    float b = bf2f(X[base + 64]);
    float c0 = cb[s * HD + d];
    float s0 = sb[s * HD + d];
    float c1 = cb[s * HD + d + 64];
    float s1 = sb[s * HD + d + 64];
    X[base]      = f2bf(a * c0 - b * s0);
    X[base + 64] = f2bf(b * c1 + a * s1);
}

// ---------------------------------------------------------------------------
// Flash attention, causal, GQA 16Q/4KV, hd=128. q-block = 64 rows (1 wave =
// 16 q-rows), k-chunk = 32, double-buffered K/V staging via global_load_lds.
// LDS trimmed to EXACTLY 32 KB (granule hypothesis: per-block LDS rounds to
// pow2 -> 32 KB gives 5 blocks/CU vs 36 KB's 2): the P LDS round-trip is
// replaced by 8x ds_bpermute_b32 + 4 cndmask (same quad redistribution:
// target (l16,Q) takes lo/hi of source lanes l16+32*(Q&1) and +16, jl=Q>>1).
// This also removes the ds_write->ds_read dependency from the serial chain.
// ---------------------------------------------------------------------------
__global__ __launch_bounds__(256, 8) void attn_kernel(
    const unsigned short* __restrict__ Q, const unsigned short* __restrict__ Kv,
    const unsigned short* __restrict__ Vt, unsigned short* __restrict__ O) {
    __shared__ __align__(16) unsigned short Kt[2][32 * 128];   // 8 KB per buf
    __shared__ __align__(16) unsigned short Vs[2][128 * 32];   // 8 KB per buf
    const int tid = threadIdx.x;
    const int wave = tid >> 6, lane = tid & 63, quad = lane >> 4, l16 = lane & 15;
    const int id = blockIdx.x;
    const int h = id & 15;
    const int grp = id >> 4, g = grp & 15, quarter = grp >> 4;
    const int qb = quarter == 0 ? 63 - g : quarter == 1 ? g
                 : quarter == 2 ? 32 + g : 31 - g;
    const int kvh = h >> 2;
    const int rowbase = qb * 64 + wave * 16;
    const float cexp = 0.08838834764831845f * 1.44269504088896f;  // scale*log2(e)
    // bpermute byte addresses for the P quad-redistribution (loop-invariant):
    // srcA = l16 + 32*(quad&1), srcB = srcA + 16.
    const int addrA = ((l16 | ((quad & 1) << 5)) << 2);
    const int addrB = addrA + 64;
    const bool upjl = (lane >= 32);   // targets in quads 2,3 take jl=1 values

    // stage chunk c (32 k-rows): K 8KB + V 8KB, 2 segs/wave each.
    auto stage = [&](int c, int b) {
        const int kb = c * 32;
#pragma unroll
        for (int u = 0; u < 2; u++) {
            const int seg = wave * 2 + u;
            const int idx = seg * 64 + lane;
            {   // K tile [32 k][128 d], 16 granules/row, swizzle cs ^ (r&15)
                const int r = idx >> 4, cs = idx & 15, cl = cs ^ (r & 15);
                async16(&Kt[b][seg * 512],
                        &Kv[(size_t)(kb + r) * QKV_N + kvh * HD + cl * 8]);
            }
            {   // V tile [128 d][32 k], 4 granules/row, swizzle cs ^ ((r>>1)&3)
                const int r = idx >> 2, cs = idx & 3, cl = cs ^ ((r >> 1) & 3);
                async16(&Vs[b][seg * 512],
                        &Vt[(size_t)(kvh * HD + r) * S_LEN + kb + cl * 8]);
            }
        }
    };

    // Q fragments (16 q-rows per wave, reused across all chunks).
    bf16x8 qf[4];
#pragma unroll
    for (int dd = 0; dd < 4; dd++)
        qf[dd] = *(const bf16x8*)&Q[(size_t)(rowbase + l16) * QKV_N +
                                     h * HD + dd * 32 + quad * 8];

    f32x4 oacc[8] = {};
    float lrow = 0.0f;
    const int qa = rowbase + l16;
    const int nch = 2 * qb + 2;

    stage(0, 0);
    __syncthreads();
    for (int c = 0; c < nch; c++) {
        const int b = c & 1;
        if (c + 1 < nch) stage(c + 1, b ^ 1);
        const int kb = c * 32;
        if (kb <= rowbase + 15) {  // per-wave skip of fully-masked chunks
            const bool diag = (kb + 31 > rowbase);
            // ---- S^T tiles tj = 0,1 (m = k-pos, n = q) ----
            f32x4 sacc[2] = {};
            __builtin_amdgcn_s_setprio(1);
#pragma unroll
            for (int dd = 0; dd < 4; dd++) {
                const int csw = (dd * 4 + quad) ^ l16;
                bf16x8 kf0 = *(const bf16x8*)&Kt[b][((0 * 16 + l16) * 16 + csw) * 8];
                bf16x8 kf1 = *(const bf16x8*)&Kt[b][((1 * 16 + l16) * 16 + csw) * 8];
                sacc[0] = mfma16(kf0, qf[dd], sacc[0]);
                sacc[1] = mfma16(kf1, qf[dd], sacc[1]);
            }
            __builtin_amdgcn_s_setprio(0);
            // ---- exp, mask, l-partials, pack 4 bf16 -> 2 dwords per tile ----
            unsigned int plo[2], phi[2];
#pragma unroll
            for (int jl = 0; jl < 2; jl++) {
                const int kg = kb + 16 * jl + 4 * quad;
                float p0 = fast_exp2(sacc[jl][0] * cexp);
                float p1 = fast_exp2(sacc[jl][1] * cexp);
                float p2 = fast_exp2(sacc[jl][2] * cexp);
                float p3 = fast_exp2(sacc[jl][3] * cexp);
                if (diag) {
                    if (kg + 0 > qa) p0 = 0.0f;
                    if (kg + 1 > qa) p1 = 0.0f;
                    if (kg + 2 > qa) p2 = 0.0f;
                    if (kg + 3 > qa) p3 = 0.0f;
                }
                lrow += (p0 + p1) + (p2 + p3);
                plo[jl] = cvt_pk_bf16(p0, p1);
                phi[jl] = cvt_pk_bf16(p2, p3);
            }
            // ---- P A-fragment via quad redistribution (no LDS) ----
            // pf dwords: d0,d1 = lo,hi of srcA; d2,d3 = lo,hi of srcB; jl=Q>>1.
            bf16x8 pf;
            {
                int a0 = __builtin_amdgcn_ds_bpermute(addrA, (int)plo[0]);
                int a1 = __builtin_amdgcn_ds_bpermute(addrA, (int)plo[1]);
                int b0 = __builtin_amdgcn_ds_bpermute(addrA, (int)phi[0]);
                int b1 = __builtin_amdgcn_ds_bpermute(addrA, (int)phi[1]);
                int c0 = __builtin_amdgcn_ds_bpermute(addrB, (int)plo[0]);
                int c1 = __builtin_amdgcn_ds_bpermute(addrB, (int)plo[1]);
                int e0 = __builtin_amdgcn_ds_bpermute(addrB, (int)phi[0]);
                int e1 = __builtin_amdgcn_ds_bpermute(addrB, (int)phi[1]);
                u32x4 t;
                t[0] = (unsigned int)(upjl ? a1 : a0);
                t[1] = (unsigned int)(upjl ? b1 : b0);
                t[2] = (unsigned int)(upjl ? c1 : c0);
                t[3] = (unsigned int)(upjl ? e1 : e0);
                pf = __builtin_bit_cast(bf16x8, t);
            }
            // ---- O += P V for this 32-k chunk ----
            const int vsw0 = (quad ^ ((l16 >> 1) & 3)) * 8;
            __builtin_amdgcn_s_setprio(1);
#pragma unroll
            for (int jd = 0; jd < 8; jd++) {
                bf16x8 vf = *(const bf16x8*)&Vs[b][(jd * 16 + l16) * 32 + vsw0];
                oacc[jd] = mfma16(pf, vf, oacc[jd]);
            }
            __builtin_amdgcn_s_setprio(0);
        }
        __syncthreads();  // drains prefetch + sync
    }
    // ---- epilogue: row sums, O /= l, write [S][NH*HD] ----
    float lsum;
    {
        float l = lrow;
        l += __shfl_xor(l, 16, 64);
        l += __shfl_xor(l, 32, 64);
        lsum = l;  // every lane: sum for q-row rowbase + l16
    }
#pragma unroll
    for (int r = 0; r < 4; r++) {
        float lq = __shfl(lsum, quad * 4 + r, 64);
        float inv = 1.0f / lq;
        int row = rowbase + quad * 4 + r;
#pragma unroll
        for (int jd = 0; jd < 8; jd++)
            O[(size_t)row * DMODEL + h * HD + jd * 16 + l16] = f2bf(oacc[jd][r] * inv);
    }
}

// ---------------------------------------------------------------------------
extern "C" void kernel_launch(void* const* d_in, const int* in_sizes, int n_in,
                              void* d_out, int out_size, void* d_ws, size_t ws_size,
                              hipStream_t stream) {
    const float* X  = (const float*)d_in[0];  // hidden [4096][2048]
    const float* cb = (const float*)d_in[1];  // cos [4096][128]
    const float* sb = (const float*)d_in[2];  // sin [4096][128]
    const float* Wq = (const float*)d_in[3];  // [2048][2048]
    const float* Wk = (const float*)d_in[4];  // [2048][512]
    const float* Wv = (const float*)d_in[5];  // [2048][512]
    const float* Wo = (const float*)d_in[6];  // [2048][2048]
    float* out = (float*)d_out;               // [4096][2048] fp32

    char* ws = (char*)d_ws;
    size_t off = 0;
    auto alloc = [&](size_t bytes) { char* p = ws + off; off += (bytes + 255) & ~(size_t)255; return p; };
    unsigned short* Xb    = (unsigned short*)alloc((size_t)S_LEN * DMODEL * 2);
    unsigned short* QKVb  = (unsigned short*)alloc((size_t)S_LEN * QKV_N * 2);   // [4096][3072]
    unsigned short* Vtb   = (unsigned short*)alloc((size_t)S_LEN * NKV * HD * 2); // [512][4096]
    unsigned short* Ob    = (unsigned short*)alloc((size_t)S_LEN * DMODEL * 2);
    unsigned short* WqkvT = (unsigned short*)alloc((size_t)QKV_N * DMODEL * 2);  // [3072][2048]
    unsigned short* WoT   = (unsigned short*)alloc((size_t)DMODEL * DMODEL * 2);

    // hidden fp32 -> bf16
    conv_f32_bf16<<<(S_LEN * DMODEL / 4 + 255) / 256, 256, 0, stream>>>(X, Xb, S_LEN * DMODEL / 4);

    dim3 tb(32, 32);
    // Weight transposes (fp32 -> bf16), stacked [Wq^T; Wk^T; Wv^T] = [3072][2048].
    transpose_f32_bf16<<<dim3(DMODEL / 32, DMODEL / 32), tb, 0, stream>>>(Wq, WqkvT, DMODEL, DMODEL);
    transpose_f32_bf16<<<dim3((NKV * HD) / 32, DMODEL / 32), tb, 0, stream>>>(Wk, WqkvT + (size_t)DMODEL * DMODEL, DMODEL, NKV * HD);
    transpose_f32_bf16<<<dim3((NKV * HD) / 32, DMODEL / 32), tb, 0, stream>>>(Wv, WqkvT + (size_t)(DMODEL + NKV * HD) * DMODEL, DMODEL, NKV * HD);
    transpose_f32_bf16<<<dim3(DMODEL / 32, DMODEL / 32), tb, 0, stream>>>(Wo, WoT, DMODEL, DMODEL);

    // Merged QKV projection: N = 3072 (cols 0..2047 Q | 2048..2559 K | 2560..3071 V)
    gemm_bt<unsigned short><<<dim3(S_LEN / 128, QKV_N / 128), 256, 0, stream>>>(Xb, WqkvT, QKVb, QKV_N, DMODEL);

    // RoPE in place: Q (stride 3072, 16 heads), K (stride 3072, 4 heads)
    rope_kernel<<<(S_LEN * NH * 64) / 256, 256, 0, stream>>>(QKVb, cb, sb, 4, QKV_N);
    rope_kernel<<<(S_LEN * NKV * 64) / 256, 256, 0, stream>>>(QKVb + DMODEL, cb, sb, 2, QKV_N);

    // V columns of QKVb -> Vt [512][4096]
    transpose_bf16<<<dim3((NKV * HD) / 32, S_LEN / 32), tb, 0, stream>>>(
        QKVb + DMODEL + NKV * HD, Vtb, S_LEN, NKV * HD, QKV_N);

    // Flash attention: 1024 blocks, 32 KB LDS -> target 5 blocks/CU
    attn_kernel<<<1024, 256, 0, stream>>>(QKVb, QKVb + DMODEL, Vtb, Ob);

    // Output projection (fp32 out)
    gemm_bt<float><<<dim3(S_LEN / 128, DMODEL / 128), 256, 0, stream>>>(Ob, WoT, out, DMODEL, DMODEL);
}